// Round 1
// baseline (453.939 us; speedup 1.0000x reference)
//
#include <hip/hip_runtime.h>
#include <cfloat>

#define CC 512   // input channels (K)
#define EE 128   // embedding (N of GEMM)
#define TM 128   // rows per block tile
#define BK 64    // K chunk
#define LDK 72   // padded LDS row length in halves (+8 to break bank aliasing, keeps 16B align)
#define NT 256

typedef _Float16 half8  __attribute__((ext_vector_type(8)));
typedef _Float16 half4v __attribute__((ext_vector_type(4)));
typedef float    floatx4 __attribute__((ext_vector_type(4)));

// Fused GEMM (fp32 -> f16 MFMA) + per-tile top3/bot3 partials.
// Grid: 1024 blocks (131072 rows / 128). Tiles never cross a batch (4096 rows/batch, 32 tiles/batch).
__global__ __launch_bounds__(NT, 2)
void weldon_gemm_topk(const float* __restrict__ x, const float* __restrict__ w,
                      float* __restrict__ part) {
  extern __shared__ char smem[];
  _Float16* As = (_Float16*)smem;           // [TM][LDK] halves  (18432 B)
  _Float16* Bs = As + TM * LDK;             // [EE][LDK] halves  (W^T: Bs[n][k]) (18432 B)
  float*    Cs = (float*)smem;              // [TM][EE] fp32 (65536 B) — aliases staging after final sync

  const int tile = blockIdx.x;
  const size_t m0 = (size_t)tile * TM;
  const int tid  = threadIdx.x;
  const int lane = tid & 63, wid = tid >> 6;
  const int q = lane >> 4, r = lane & 15;

  floatx4 acc[2][8];
  const floatx4 zero = {0.f, 0.f, 0.f, 0.f};
  #pragma unroll
  for (int i = 0; i < 2; ++i)
    #pragma unroll
    for (int j = 0; j < 8; ++j)
      acc[i][j] = zero;

  for (int kc = 0; kc < CC / BK; ++kc) {
    const int k0 = kc * BK;
    __syncthreads();
    // Stage A: 128 rows x 64 cols fp32 -> f16. 2048 float4 / 256 threads = 8 each.
    #pragma unroll
    for (int it = 0; it < 8; ++it) {
      int idx = it * NT + tid;
      int row = idx >> 4;
      int c4  = (idx & 15) << 2;
      float4 v = *(const float4*)(x + (m0 + row) * CC + k0 + c4);
      half4v h;
      h.x = (_Float16)v.x; h.y = (_Float16)v.y; h.z = (_Float16)v.z; h.w = (_Float16)v.w;
      *(half4v*)(As + row * LDK + c4) = h;
    }
    // Stage W^T: W[k][n] -> Bs[n][k]. 64x128 fp32 = 2048 float4 / 256 threads = 8 each.
    #pragma unroll
    for (int it = 0; it < 8; ++it) {
      int idx = it * NT + tid;
      int kr = idx >> 5;
      int n4 = (idx & 31) << 2;
      float4 v = *(const float4*)(w + (k0 + kr) * EE + n4);
      Bs[(n4 + 0) * LDK + kr] = (_Float16)v.x;
      Bs[(n4 + 1) * LDK + kr] = (_Float16)v.y;
      Bs[(n4 + 2) * LDK + kr] = (_Float16)v.z;
      Bs[(n4 + 3) * LDK + kr] = (_Float16)v.w;
    }
    __syncthreads();
    // MFMA: each wave computes rows [wid*32, wid*32+32) x all 128 cols.
    #pragma unroll
    for (int kk = 0; kk < 2; ++kk) {
      const int ko = kk * 32 + q * 8;
      half8 a[2], b[8];
      #pragma unroll
      for (int rt = 0; rt < 2; ++rt)
        a[rt] = *(const half8*)(As + (wid * 32 + rt * 16 + r) * LDK + ko);
      #pragma unroll
      for (int ct = 0; ct < 8; ++ct)
        b[ct] = *(const half8*)(Bs + (ct * 16 + r) * LDK + ko);
      #pragma unroll
      for (int rt = 0; rt < 2; ++rt)
        #pragma unroll
        for (int ct = 0; ct < 8; ++ct)
          acc[rt][ct] = __builtin_amdgcn_mfma_f32_16x16x32_f16(a[rt], b[ct], acc[rt][ct], 0, 0, 0);
    }
  }
  __syncthreads();  // all MFMA LDS reads done; safe to alias Cs over staging
  // C/D layout (m89/m91 verified): col = lane&15, row = (lane>>4)*4 + reg
  #pragma unroll
  for (int rt = 0; rt < 2; ++rt)
    #pragma unroll
    for (int ct = 0; ct < 8; ++ct) {
      int col  = ct * 16 + r;
      int rowb = wid * 32 + rt * 16 + q * 4;
      #pragma unroll
      for (int g = 0; g < 4; ++g)
        Cs[(rowb + g) * EE + col] = acc[rt][ct][g];
    }
  __syncthreads();
  // Column scan: thread e keeps branchless top3/bot3 over 128 rows.
  if (tid < EE) {
    float t0 = -FLT_MAX, t1 = -FLT_MAX, t2 = -FLT_MAX;
    float b0 =  FLT_MAX, b1 =  FLT_MAX, b2 =  FLT_MAX;
    for (int rr = 0; rr < TM; ++rr) {
      float v = Cs[rr * EE + tid];
      float m  = fminf(t0, v);  t0 = fmaxf(t0, v);
      float m2 = fminf(t1, m);  t1 = fmaxf(t1, m);
      t2 = fmaxf(t2, m2);
      float M  = fmaxf(b0, v);  b0 = fminf(b0, v);
      float M2 = fmaxf(b1, M);  b1 = fminf(b1, M);
      b2 = fminf(b2, M2);
    }
    float* p = part + ((size_t)tile * EE + tid) * 6;
    p[0] = t0; p[1] = t1; p[2] = t2;
    p[3] = b0; p[4] = b1; p[5] = b2;
  }
}

// Merge 32 chunk-partials per (b,e), pool, L2-normalize per b.
__global__ __launch_bounds__(128)
void weldon_merge(const float* __restrict__ part, float* __restrict__ out) {
  const int b = blockIdx.x;   // 0..31
  const int e = threadIdx.x;  // 0..127
  float t0 = -FLT_MAX, t1 = -FLT_MAX, t2 = -FLT_MAX;
  float b0 =  FLT_MAX, b1 =  FLT_MAX, b2 =  FLT_MAX;
  for (int c = 0; c < 32; ++c) {
    const float* p = part + ((size_t)((b * 32 + c) * EE + e)) * 6;
    #pragma unroll
    for (int j = 0; j < 3; ++j) {
      float v = p[j];
      float m  = fminf(t0, v);  t0 = fmaxf(t0, v);
      float m2 = fminf(t1, m);  t1 = fmaxf(t1, m);
      t2 = fmaxf(t2, m2);
    }
    #pragma unroll
    for (int j = 3; j < 6; ++j) {
      float v = p[j];
      float M  = fmaxf(b0, v);  b0 = fminf(b0, v);
      float M2 = fmaxf(b1, M);  b1 = fminf(b1, M);
      b2 = fminf(b2, M2);
    }
  }
  float pooled = t0 + t1 + t2 + b0 + b1 + b2;
  float sq = pooled * pooled;
  #pragma unroll
  for (int m = 1; m < 64; m <<= 1) sq += __shfl_xor(sq, m, 64);
  __shared__ float red[2];
  if ((e & 63) == 0) red[e >> 6] = sq;
  __syncthreads();
  float total = red[0] + red[1];
  out[b * EE + e] = pooled * rsqrtf(fmaxf(total, 1e-12f));
}

extern "C" void kernel_launch(void* const* d_in, const int* in_sizes, int n_in,
                              void* d_out, int out_size, void* d_ws, size_t ws_size,
                              hipStream_t stream) {
  const float* x = (const float*)d_in[0];  // [32,64,64,512] fp32
  const float* w = (const float*)d_in[1];  // [512,128] fp32
  float* out  = (float*)d_out;             // [32,128] fp32
  float* part = (float*)d_ws;              // 1024 tiles * 128 e * 6 floats = 3 MB

  // LDS: max(staging 36864 B, C-tile 65536 B) = 65536 B (aliased regions)
  weldon_gemm_topk<<<dim3(1024), dim3(NT), 65536, stream>>>(x, w, part);
  weldon_merge<<<dim3(32), dim3(128), 0, stream>>>(part, out);
}

// Round 3
// 372.619 us; speedup vs baseline: 1.2182x; 1.2182x over previous
//
#include <hip/hip_runtime.h>
#include <cfloat>

#define CC 512   // K (input channels)
#define EE 128   // embedding cols
#define NTH 512  // threads/block (8 waves)
#define TM 256   // rows per block (32 per wave)
#define NBLK 512 // 131072 / 256

typedef _Float16 half8 __attribute__((ext_vector_type(8)));
typedef float floatx4 __attribute__((ext_vector_type(4)));

__device__ __forceinline__ void ins_top(float v, float& t0, float& t1, float& t2) {
  float m  = fminf(t0, v); t0 = fmaxf(t0, v);
  float m2 = fminf(t1, m); t1 = fmaxf(t1, m);
  t2 = fmaxf(t2, m2);
}
__device__ __forceinline__ void ins_bot(float v, float& b0, float& b1, float& b2) {
  float M  = fmaxf(b0, v); b0 = fminf(b0, v);
  float M2 = fmaxf(b1, M); b1 = fminf(b1, M);
  b2 = fminf(b2, M2);
}

// Fused GEMM (fp32->f16 MFMA) + per-block top3/bot3 partials.
// A (x) fragments come straight from global (no LDS staging, no K-loop barriers
// within a 256-K phase). W staged to LDS as Wl[kg][n][8] f16, 2 phases.
__global__ __launch_bounds__(NTH, 4)
void weldon_main(const float* __restrict__ x, const float* __restrict__ w,
                 float* __restrict__ part) {
  extern __shared__ char smem[];
  _Float16* Wl = (_Float16*)smem;   // [32][128][8] halves = 65536 B per phase
  float*    scr = (float*)smem;     // epilogue scratch [8][128][6] floats (24 KB), aliased

  const int tid  = threadIdx.x;
  const int lane = tid & 63, wid = tid >> 6;
  const int q = lane >> 4, r = lane & 15;
  const size_t rbase = (size_t)blockIdx.x * TM + wid * 32;

  floatx4 acc[2][8];
  const floatx4 zero = {0.f, 0.f, 0.f, 0.f};
  #pragma unroll
  for (int i = 0; i < 2; ++i)
    #pragma unroll
    for (int j = 0; j < 8; ++j) acc[i][j] = zero;

  const float* ap0 = x + (rbase + r) * CC + q * 8;       // rt=0 row
  const float* ap1 = ap0 + (size_t)16 * CC;              // rt=1 row

  float4 buf[2][2][2];  // [slot][rt][half] — register double buffer for A
  buf[0][0][0] = *(const float4*)(ap0);
  buf[0][0][1] = *(const float4*)(ap0 + 4);
  buf[0][1][0] = *(const float4*)(ap1);
  buf[0][1][1] = *(const float4*)(ap1 + 4);

  #pragma unroll
  for (int ks = 0; ks < 16; ++ks) {
    if ((ks & 7) == 0) {
      __syncthreads();
      // Stage W phase ph = ks>>3: k in [ph*256, ph*256+256).
      // 32 kg-groups x 128 n = 4096 half8 entries; 512 threads x 8 passes.
      // Scalar coalesced reads, conflict-free ds_write_b128 (16 B lane stride).
      const float* wp = w + (size_t)(ks >> 3) * 256 * EE;
      #pragma unroll
      for (int pass = 0; pass < 8; ++pass) {
        int kg = pass * 4 + (tid >> 7);   // 0..31 (local k-group of 8)
        int n  = tid & 127;
        half8 h;
        #pragma unroll
        for (int j = 0; j < 8; ++j)
          h[j] = (_Float16)wp[(size_t)(kg * 8 + j) * EE + n];
        *(half8*)(Wl + ((size_t)kg * 128 + n) * 8) = h;
      }
      __syncthreads();
    }
    const int cur = ks & 1, nxt = cur ^ 1;
    if (ks < 15) {  // prefetch next K-step's A into the other slot
      const float* p0 = ap0 + (ks + 1) * 32;
      const float* p1 = ap1 + (ks + 1) * 32;
      buf[nxt][0][0] = *(const float4*)(p0);
      buf[nxt][0][1] = *(const float4*)(p0 + 4);
      buf[nxt][1][0] = *(const float4*)(p1);
      buf[nxt][1][1] = *(const float4*)(p1 + 4);
    }
    half8 a[2];
    #pragma unroll
    for (int rt = 0; rt < 2; ++rt) {
      float4 v0 = buf[cur][rt][0], v1 = buf[cur][rt][1];
      a[rt][0] = (_Float16)v0.x; a[rt][1] = (_Float16)v0.y;
      a[rt][2] = (_Float16)v0.z; a[rt][3] = (_Float16)v0.w;
      a[rt][4] = (_Float16)v1.x; a[rt][5] = (_Float16)v1.y;
      a[rt][6] = (_Float16)v1.z; a[rt][7] = (_Float16)v1.w;
    }
    // b-frag: lane needs W^T[n = ct*16+r][k = ks*32 + q*8 + j] = Wl[kg][n][j]
    const _Float16* bp = Wl + ((size_t)((ks & 7) * 4 + q) * 128 + r) * 8;
    #pragma unroll
    for (int ct = 0; ct < 8; ++ct) {
      half8 b = *(const half8*)(bp + (size_t)ct * 16 * 8);
      acc[0][ct] = __builtin_amdgcn_mfma_f32_16x16x32_f16(a[0], b, acc[0][ct], 0, 0, 0);
      acc[1][ct] = __builtin_amdgcn_mfma_f32_16x16x32_f16(a[1], b, acc[1][ct], 0, 0, 0);
    }
  }

  __syncthreads();  // all Wl reads done; scr may alias

  // Per-lane top3/bot3 over its 8 rows per column group, butterfly-merge over q.
  // C/D layout: col = ct*16 + (lane&15), row = wid*32 + rt*16 + (lane>>4)*4 + g.
  #pragma unroll
  for (int ct = 0; ct < 8; ++ct) {
    float t0 = -FLT_MAX, t1 = -FLT_MAX, t2 = -FLT_MAX;
    float b0 =  FLT_MAX, b1 =  FLT_MAX, b2 =  FLT_MAX;
    #pragma unroll
    for (int rt = 0; rt < 2; ++rt)
      #pragma unroll
      for (int g = 0; g < 4; ++g) {
        float v = acc[rt][ct][g];
        ins_top(v, t0, t1, t2);
        ins_bot(v, b0, b1, b2);
      }
    #pragma unroll
    for (int mask = 16; mask <= 32; mask <<= 1) {
      float o0 = __shfl_xor(t0, mask), o1 = __shfl_xor(t1, mask), o2 = __shfl_xor(t2, mask);
      ins_top(o0, t0, t1, t2); ins_top(o1, t0, t1, t2); ins_top(o2, t0, t1, t2);
      float p0 = __shfl_xor(b0, mask), p1 = __shfl_xor(b1, mask), p2 = __shfl_xor(b2, mask);
      ins_bot(p0, b0, b1, b2); ins_bot(p1, b0, b1, b2); ins_bot(p2, b0, b1, b2);
    }
    if ((ct >> 1) == q) {  // each col written once per wave
      float* p = scr + ((size_t)wid * 128 + ct * 16 + r) * 6;
      p[0] = t0; p[1] = t1; p[2] = t2; p[3] = b0; p[4] = b1; p[5] = b2;
    }
  }
  __syncthreads();

  if (tid < EE) {  // merge 8 waves -> block partial for column tid
    float t0 = -FLT_MAX, t1 = -FLT_MAX, t2 = -FLT_MAX;
    float b0 =  FLT_MAX, b1 =  FLT_MAX, b2 =  FLT_MAX;
    #pragma unroll
    for (int wv = 0; wv < 8; ++wv) {
      const float* p = scr + ((size_t)wv * 128 + tid) * 6;
      ins_top(p[0], t0, t1, t2); ins_top(p[1], t0, t1, t2); ins_top(p[2], t0, t1, t2);
      ins_bot(p[3], b0, b1, b2); ins_bot(p[4], b0, b1, b2); ins_bot(p[5], b0, b1, b2);
    }
    float* p = part + ((size_t)blockIdx.x * EE + tid) * 6;
    p[0] = t0; p[1] = t1; p[2] = t2; p[3] = b0; p[4] = b1; p[5] = b2;
  }
}

// Merge 16 chunk-partials per (b,e), pool, L2-normalize per b.
__global__ __launch_bounds__(128)
void weldon_merge(const float* __restrict__ part, float* __restrict__ out) {
  const int b = blockIdx.x;   // 0..31
  const int e = threadIdx.x;  // 0..127
  float t0 = -FLT_MAX, t1 = -FLT_MAX, t2 = -FLT_MAX;
  float b0 =  FLT_MAX, b1 =  FLT_MAX, b2 =  FLT_MAX;
  #pragma unroll
  for (int c = 0; c < 16; ++c) {
    const float* p = part + ((size_t)((b * 16 + c) * EE + e)) * 6;
    ins_top(p[0], t0, t1, t2); ins_top(p[1], t0, t1, t2); ins_top(p[2], t0, t1, t2);
    ins_bot(p[3], b0, b1, b2); ins_bot(p[4], b0, b1, b2); ins_bot(p[5], b0, b1, b2);
  }
  float pooled = t0 + t1 + t2 + b0 + b1 + b2;
  float sq = pooled * pooled;
  #pragma unroll
  for (int m = 1; m < 64; m <<= 1) sq += __shfl_xor(sq, m, 64);
  __shared__ float red[2];
  if ((e & 63) == 0) red[e >> 6] = sq;
  __syncthreads();
  float total = red[0] + red[1];
  out[b * EE + e] = pooled * rsqrtf(fmaxf(total, 1e-12f));
}

extern "C" void kernel_launch(void* const* d_in, const int* in_sizes, int n_in,
                              void* d_out, int out_size, void* d_ws, size_t ws_size,
                              hipStream_t stream) {
  const float* x = (const float*)d_in[0];  // [32,64,64,512] fp32
  const float* w = (const float*)d_in[1];  // [512,128] fp32
  float* out  = (float*)d_out;             // [32,128] fp32
  float* part = (float*)d_ws;              // 512 tiles * 128 * 6 floats = 1.5 MB

  weldon_main<<<dim3(NBLK), dim3(NTH), 65536, stream>>>(x, w, part);
  weldon_merge<<<dim3(32), dim3(128), 0, stream>>>(part, out);
}